// Round 7
// baseline (78.623 us; speedup 1.0000x reference)
//
#include <hip/hip_runtime.h>
#include <cmath>

#define B_ 16
#define H_ 32
#define W_ 32
#define C_ 128
#define F_ 128
#define KSZ (9*C_*F_)        // 147456 elems per effective kernel
#define NKS 36               // K-steps of 32 (9 taps x 4 c-chunks)
#define FRAG_ELE 4096        // elems per K-step fragment chunk

typedef __bf16 bf16;
typedef __bf16 bf16x4 __attribute__((ext_vector_type(4)));
typedef __bf16 bf16x8 __attribute__((ext_vector_type(8)));
typedef float  f32x4  __attribute__((ext_vector_type(4)));

__device__ __forceinline__ float softplus_f(float v) {
  return log1pf(expf(-fabsf(v))) + fmaxf(v, 0.f);
}

// top-2 softmax gates from 8 logits (ties -> lowest index, = lax.top_k)
__device__ __forceinline__ void top2_gates_f(const float* lg, float* gl) {
  int i0 = 0;
  #pragma unroll
  for (int e = 1; e < 8; ++e) if (lg[e] > lg[i0]) i0 = e;
  int i1 = (i0 == 0) ? 1 : 0;
  #pragma unroll
  for (int e = 0; e < 8; ++e) if (e != i0 && lg[e] > lg[i1]) i1 = e;
  float m  = fmaxf(lg[i0], lg[i1]);
  float e0 = expf(lg[i0] - m), e1 = expf(lg[i1] - m);
  float s  = e0 + e1;
  #pragma unroll
  for (int e = 0; e < 8; ++e) gl[e] = 0.f;
  gl[i0] = e0 / s; gl[i1] = e1 / s;
}

// logit for batch bb, expert e from conv<2> partials (32 per batch now).
// Bit-identical op order at every call site -> consistent gates everywhere.
__device__ __forceinline__ float logit_f(const float* part, const float* gob,
                                         const float* epsg, int bb, int e) {
  float s = 0.f;
  #pragma unroll
  for (int p = 0; p < 32; ++p) s += part[(bb*32 + p)*8 + e];
  return s + gob[e] + 1e-4f * epsg[bb*8 + e];
}

// XCD-aware block -> (batch, h-pair, n-half). Dispatch round-robins bid over
// the 8 XCDs, so batch b's 32 blocks land on XCD b&7 -> per-XCD hot B set =
// 2 batches' kernels, fits the 4MB XCD L2. [T1; FETCH 79->58MB r4->r5]
__device__ __forceinline__ void block_map_f(int bid, int* b, int* hb, int* nh) {
  *b  = (bid & 7) * 2 + (bid >> 8);
  *hb = (bid >> 3) & 15;
  *nh = (bid >> 7) & 1;
}

// ---------------------------------------------------------------------------
// MFMA 3x3 SAME conv, block = (b, h-pair, n-half): M=64 (2h x 32w), N=64,
// K=1152. Grid 512 -> 2 blocks/CU, 4 waves/SIMD (r6 was 1 block/CU, latency-
// bound). 8 waves: wave = m-frag (hl=h-row, wh=w-half) x 2 n-frags.
// Per-CU LDS reads/K-step unchanged vs r6 (16/block x 2 blocks); m-frag-
// duplicate B loads hit L1 -> L2 traffic also at parity.
// A: x staged f32->bf16 (hi[,lo]) into XOR-swizzled LDS; one barrier.
// B: fragment-ordered global [ks][nf][lane][8]; 3-slot register pipeline
//    (in-flight: NVAR=1 24 / NVAR=2 48 VGPR; acc only 8 -> fits 128 budget;
//    4-6 deep spilled in r4/r5: 111MB scratch writes).
// NVAR==2: split-precision gating conv (Ah*Bh + Al*Bh + Ah*Bl), epilogue
//          fuses 2x2 maxpool (h-max via LDS, aliased on xs) + dense partials.
// NVAR==1: expert conv, per-batch B; gates+effective-bias computed in-block.
// ---------------------------------------------------------------------------
template<int NVAR>
__global__ __launch_bounds__(512, 4) void conv_k(
    const float* __restrict__ x,
    const bf16* __restrict__ Bhi, const bf16* __restrict__ Blo,
    const float* __restrict__ gb,    // gating conv bias     (NVAR==2)
    const float* __restrict__ Wg,    // gating dense weights (NVAR==2)
    const float* __restrict__ part,  // logit partials       (NVAR==1)
    const float* __restrict__ gob,   // gating out bias      (NVAR==1)
    const float* __restrict__ epsg,  // gate noise           (NVAR==1)
    const float* __restrict__ ebias, // expert bias [F][8]   (NVAR==1)
    float* __restrict__ outv)
{
  int b, hb, nh;
  block_map_f(blockIdx.x, &b, &hb, &nh);
  const int t = threadIdx.x;

  __shared__ bf16 xs[NVAR*4*34*128];   // 34816 B per variant, swizzled
  __shared__ float red[8][8];
  __shared__ float gl8[8];

  // ---- stage x (4 rows x 34 cols x 128c), f32 -> bf16 hi(/lo), swizzled ----
  for (int v = t; v < 4*34*32; v += 512) {
    int c4   = v & 31;
    int col  = (v >> 5) % 34;
    int rowi = (v >> 5) / 34;
    int row  = hb*2 - 1 + rowi;
    int w    = col - 1;
    float4 xv = make_float4(0.f, 0.f, 0.f, 0.f);
    if (row >= 0 && row < H_ && w >= 0 && w < W_)
      xv = *(const float4*)&x[((b*H_ + row)*W_ + w)*C_ + c4*4];
    float vv[4] = {xv.x, xv.y, xv.z, xv.w};
    bf16x4 h4, l4;
    #pragma unroll
    for (int j = 0; j < 4; ++j) {
      h4[j] = (bf16)vv[j];
      if (NVAR == 2) l4[j] = (bf16)(vv[j] - (float)h4[j]);
    }
    int base = ((rowi*34 + col)*256 + c4*8) ^ ((col & 7) << 4);
    *(bf16x4*)((char*)xs + base) = h4;
    if (NVAR == 2) *(bf16x4*)((char*)xs + 34816 + base) = l4;
  }
  if (NVAR == 1 && t == 0) {           // gates for this batch (pre-barrier)
    float lg[8], gg[8];
    #pragma unroll
    for (int e = 0; e < 8; ++e) lg[e] = logit_f(part, gob, epsg, b, e);
    top2_gates_f(lg, gg);
    #pragma unroll
    for (int e = 0; e < 8; ++e) gl8[e] = gg[e];
  }
  __syncthreads();

  const int l    = t & 63;
  const int wid  = t >> 6;
  const int mq   = wid & 3;            // m-frag: hl = mq>>1, wh = mq&1
  const int hl   = mq >> 1;
  const int wh   = mq & 1;
  const int nfp  = wid >> 2;           // n-pair within this block's n-half
  const int r15  = l & 15;
  const int q    = l >> 4;

  f32x4 acc0 = {0.f,0.f,0.f,0.f}, acc1 = acc0;

  const bf16* Bh = Bhi + (NVAR == 1 ? (size_t)b * KSZ : (size_t)0);
  const size_t bgo = (size_t)((nh*4 + nfp*2)*512 + l*8);

  bf16x8 s0h0,s0h1,s0l0,s0l1, s1h0,s1h1,s1l0,s1l1, s2h0,s2h1,s2l0,s2l1;

#define LOADB(S, KS_) do {                                                  \
    int kk_ = (KS_); if (kk_ > NKS-1) kk_ = NKS-1;                          \
    size_t o_ = bgo + (size_t)kk_ * FRAG_ELE;                               \
    S##h0 = *(const bf16x8*)(Bh + o_);                                      \
    S##h1 = *(const bf16x8*)(Bh + o_ + 512);                                \
    if (NVAR == 2) {                                                        \
      S##l0 = *(const bf16x8*)(Blo + o_);                                   \
      S##l1 = *(const bf16x8*)(Blo + o_ + 512);                             \
    }                                                                       \
  } while (0)

#define MFMA16(a, bb_, c) __builtin_amdgcn_mfma_f32_16x16x32_bf16(a, bb_, c, 0, 0, 0)

#define COMPUTE(S, KS_) do {                                                \
    const int khkw_ = (KS_) >> 2;                                           \
    const int kh_ = khkw_ / 3, kw_ = khkw_ % 3;                             \
    const int c0_ = ((KS_) & 3) << 5;                                       \
    const int col_ = wh*16 + r15 + kw_;                                     \
    const int off_ = (((kh_ + hl)*34 + col_)*256 + (c0_ + q*8)*2)           \
                     ^ ((col_ & 7) << 4);                                   \
    bf16x8 a_hi = *(const bf16x8*)((const char*)xs + off_);                 \
    __builtin_amdgcn_s_setprio(1);                                          \
    acc0 = MFMA16(a_hi, S##h0, acc0);                                       \
    acc1 = MFMA16(a_hi, S##h1, acc1);                                       \
    if (NVAR == 2) {                                                        \
      bf16x8 a_lo = *(const bf16x8*)((const char*)xs + 34816 + off_);       \
      acc0 = MFMA16(a_lo, S##h0, acc0);                                     \
      acc1 = MFMA16(a_lo, S##h1, acc1);                                     \
      acc0 = MFMA16(a_hi, S##l0, acc0);                                     \
      acc1 = MFMA16(a_hi, S##l1, acc1);                                     \
    }                                                                       \
    __builtin_amdgcn_s_setprio(0);                                          \
  } while (0)

  LOADB(s0, 0); LOADB(s1, 1); LOADB(s2, 2);
  for (int ks = 0; ks < NKS; ks += 3) {
    COMPUTE(s0, ks);   LOADB(s0, ks+3);
    COMPUTE(s1, ks+1); LOADB(s1, ks+4);
    COMPUTE(s2, ks+2); LOADB(s2, ks+5);
  }
#undef LOADB
#undef COMPUTE

  // C/D layout: col(f) = l&15, row(m within frag) = q*4 + r
  if (NVAR == 1) {
    const int f0 = nh*64 + nfp*32 + r15;
    float bv0 = 0.f, bv1 = 0.f;
    #pragma unroll
    for (int e = 0; e < 8; ++e) {
      bv0 += gl8[e] * ebias[f0*8 + e];
      bv1 += gl8[e] * ebias[(f0+16)*8 + e];
    }
    const int h = hb*2 + hl;
    #pragma unroll
    for (int r = 0; r < 4; ++r) {
      const int wo = wh*16 + q*4 + r;
      float* o = &outv[((b*H_ + h)*W_ + wo)*F_];
      o[f0]      = acc0[r] + bv0;
      o[f0 + 16] = acc1[r] + bv1;
    }
  } else {
    // ---- fused 2x2 maxpool + dense partials ----
    __syncthreads();                          // all xs reads done
    float* hpool = (float*)xs;                // [2 hl][16 pw][64 fl], 8KB
    #pragma unroll
    for (int ni = 0; ni < 2; ++ni) {
      const int fl = nfp*32 + ni*16 + r15;
      #pragma unroll
      for (int pp = 0; pp < 2; ++pp) {
        float mw = ni ? fmaxf(acc1[2*pp], acc1[2*pp+1])
                      : fmaxf(acc0[2*pp], acc0[2*pp+1]);
        const int pw = wh*8 + q*2 + pp;
        hpool[(hl*16 + pw)*64 + fl] = mw;
      }
    }
    __syncthreads();
    float pr[8] = {0,0,0,0,0,0,0,0};
    if (hl == 0) {
      #pragma unroll
      for (int ni = 0; ni < 2; ++ni) {
        const int fl = nfp*32 + ni*16 + r15;
        const float bv = gb[nh*64 + fl];
        #pragma unroll
        for (int pp = 0; pp < 2; ++pp) {
          const int pw = wh*8 + q*2 + pp;
          float pm = fmaxf(hpool[pw*64 + fl], hpool[(16 + pw)*64 + fl]) + bv;
          const float* wr = &Wg[(size_t)((hb*16 + pw)*128 + nh*64 + fl) * 8];
          float4 wA = *(const float4*)wr;
          float4 wB = *(const float4*)(wr + 4);
          pr[0] += pm*wA.x; pr[1] += pm*wA.y; pr[2] += pm*wA.z; pr[3] += pm*wA.w;
          pr[4] += pm*wB.x; pr[5] += pm*wB.y; pr[6] += pm*wB.z; pr[7] += pm*wB.w;
        }
      }
    }
    #pragma unroll
    for (int o = 32; o > 0; o >>= 1)
      #pragma unroll
      for (int e = 0; e < 8; ++e) pr[e] += __shfl_down(pr[e], o);
    if (l == 0)
      #pragma unroll
      for (int e = 0; e < 8; ++e) red[wid][e] = pr[e];
    __syncthreads();
    if (t < 8) {
      float s = 0.f;
      #pragma unroll
      for (int w = 0; w < 8; ++w) s += red[w][t];   // hl==1 rows are zero
      outv[(b*32 + hb*2 + nh)*8 + t] = s;   // partial logits (32 per batch)
    }
  }
}

// ---------------------------------------------------------------------------
// Effective per-batch kernels in bf16 MFMA fragment order; gates recomputed
// in-block from partials. Block = (ks, nf-half, batch-quarter): grid 288.
// ---------------------------------------------------------------------------
__global__ __launch_bounds__(256) void effk_k(
    const float* __restrict__ mu, const float* __restrict__ rho,
    const float* __restrict__ eps,
    const float* __restrict__ part, const float* __restrict__ gob,
    const float* __restrict__ epsg,
    bf16* __restrict__ Bg)
{
  const int ks  = blockIdx.x >> 3;
  const int rem = blockIdx.x & 7;
  const int t   = threadIdx.x;
  const int nf  = (rem & 1)*4 + (t >> 6);
  const int bq  = (rem >> 1) * 4;

  __shared__ float lgs[4][8];
  __shared__ float gl[4][8];
  if (t < 32) lgs[t >> 3][t & 7] = logit_f(part, gob, epsg, bq + (t >> 3), t & 7);
  __syncthreads();
  if (t < 4) top2_gates_f(lgs[t], gl[t]);
  __syncthreads();

  const int l    = t & 63;
  const int khkw = ks >> 2;
  const int kw   = khkw % 3;
  const int f    = nf*16 + (l & 15);
  const int cb   = (ks & 3)*32 + (l >> 4)*8;

  bf16x8 ob[4];
  #pragma unroll
  for (int j = 0; j < 8; ++j) {
    const int c = cb + j;
    const float* mp = &mu [(size_t)((khkw*C_ + c)*F_ + f) * 8];
    const float* ep = &eps[(size_t)((khkw*C_ + c)*F_ + f) * 8];
    const float* rp = &rho[(size_t)((kw  *C_ + c)*F_ + f) * 8];
    float kv[8];
    #pragma unroll
    for (int e = 0; e < 8; ++e)
      kv[e] = mp[e] + softplus_f(rp[e]) * ep[e];
    #pragma unroll
    for (int bb = 0; bb < 4; ++bb) {
      float s = 0.f;
      #pragma unroll
      for (int e = 0; e < 8; ++e) s += gl[bb][e] * kv[e];
      ob[bb][j] = (bf16)s;
    }
  }
  #pragma unroll
  for (int bb = 0; bb < 4; ++bb) {
    size_t o = (size_t)(bq + bb)*KSZ + (size_t)ks*FRAG_ELE + nf*512 + l*8;
    *(bf16x8*)&Bg[o] = ob[bb];
  }
}

// ---------------------------------------------------------------------------
// gating_kernel f32 -> bf16 hi/lo in fragment order, via coalesced tile load
// + LDS transpose (stride 129: conflict-free reads). Block = one K-step.
// ---------------------------------------------------------------------------
__global__ __launch_bounds__(512) void gkconv_k(
    const float* __restrict__ gk, bf16* __restrict__ bgh, bf16* __restrict__ bgl)
{
  __shared__ float tile[32*129];
  const int ks   = blockIdx.x;
  const int khkw = ks >> 2;
  const int cb   = (ks & 3)*32;
  const int t    = threadIdx.x;

  for (int v = t; v < 1024; v += 512) {          // 32c x 128f, coalesced
    int c  = v >> 5;
    int f4 = (v & 31) * 4;
    float4 val = *(const float4*)&gk[(size_t)(khkw*C_ + cb + c)*F_ + f4];
    float* dst = &tile[c*129 + f4];
    dst[0] = val.x; dst[1] = val.y; dst[2] = val.z; dst[3] = val.w;
  }
  __syncthreads();

  const int nf = t >> 6, l = t & 63;
  const int f  = nf*16 + (l & 15);
  bf16x8 h8, l8;
  #pragma unroll
  for (int j = 0; j < 8; ++j) {
    int c = (l >> 4)*8 + j;
    float v = tile[c*129 + f];
    bf16 h = (bf16)v;
    h8[j] = h;
    l8[j] = (bf16)(v - (float)h);
  }
  *(bf16x8*)&bgh[(size_t)ks*FRAG_ELE + t*8] = h8;
  *(bf16x8*)&bgl[(size_t)ks*FRAG_ELE + t*8] = l8;
}

// ---------------------------------------------------------------------------
extern "C" void kernel_launch(void* const* d_in, const int* in_sizes, int n_in,
                              void* d_out, int out_size, void* d_ws, size_t ws_size,
                              hipStream_t stream) {
  const float* x    = (const float*)d_in[0];
  const float* epsk = (const float*)d_in[1];
  const float* epsg = (const float*)d_in[2];
  const float* mu   = (const float*)d_in[3];
  const float* rho  = (const float*)d_in[4];
  const float* ebias= (const float*)d_in[5];
  const float* gk   = (const float*)d_in[6];
  const float* gb   = (const float*)d_in[7];
  const float* gok  = (const float*)d_in[8];
  const float* gob  = (const float*)d_in[9];
  float* out = (float*)d_out;

  char* ws = (char*)d_ws;
  bf16*  bgh  = (bf16*) (ws);                   //   294,912 B
  bf16*  bgl  = (bf16*) (ws + 294912);          //   294,912 B
  bf16*  bge  = (bf16*) (ws + 589824);          // 4,718,592 B
  float* part = (float*)(ws + 5308416);         //    16,384 B  (~5.3 MB)

  // 1. gating kernel -> bf16 hi/lo fragment order (coalesced)
  gkconv_k<<<NKS, 512, 0, stream>>>(gk, bgh, bgl);
  // 2. gating conv (split bf16, fused pool + dense partials)
  conv_k<2><<<512, 512, 0, stream>>>(x, bgh, bgl, gb, gok,
                                     nullptr, nullptr, nullptr, nullptr, part);
  // 3. per-batch effective kernel (gates recomputed in-block)
  effk_k<<<NKS*8, 256, 0, stream>>>(mu, rho, epsk, part, gob, epsg, bge);
  // 4. expert conv (per-batch kernel; gates + effective bias in-block)
  conv_k<1><<<512, 512, 0, stream>>>(x, bge, bge, nullptr, nullptr,
                                     part, gob, epsg, ebias, out);
}

// Round 8
// 70.264 us; speedup vs baseline: 1.1190x; 1.1190x over previous
//
#include <hip/hip_runtime.h>
#include <cmath>

#define B_ 16
#define H_ 32
#define W_ 32
#define C_ 128
#define F_ 128
#define KSZ (9*C_*F_)        // 147456 elems per effective kernel
#define NKS 36               // K-steps of 32 (9 taps x 4 c-chunks)
#define FRAG_ELE 4096        // elems per K-step fragment chunk

typedef __bf16 bf16;
typedef __bf16 bf16x4 __attribute__((ext_vector_type(4)));
typedef __bf16 bf16x8 __attribute__((ext_vector_type(8)));
typedef float  f32x4  __attribute__((ext_vector_type(4)));

__device__ __forceinline__ float softplus_f(float v) {
  return log1pf(expf(-fabsf(v))) + fmaxf(v, 0.f);
}

// top-2 softmax gates from 8 logits (ties -> lowest index, = lax.top_k)
__device__ __forceinline__ void top2_gates_f(const float* lg, float* gl) {
  int i0 = 0;
  #pragma unroll
  for (int e = 1; e < 8; ++e) if (lg[e] > lg[i0]) i0 = e;
  int i1 = (i0 == 0) ? 1 : 0;
  #pragma unroll
  for (int e = 0; e < 8; ++e) if (e != i0 && lg[e] > lg[i1]) i1 = e;
  float m  = fmaxf(lg[i0], lg[i1]);
  float e0 = expf(lg[i0] - m), e1 = expf(lg[i1] - m);
  float s  = e0 + e1;
  #pragma unroll
  for (int e = 0; e < 8; ++e) gl[e] = 0.f;
  gl[i0] = e0 / s; gl[i1] = e1 / s;
}

// logit for batch bb, expert e from conv<2> partials (16 per batch).
// Bit-identical op order at every call site -> consistent gates everywhere.
__device__ __forceinline__ float logit_f(const float* part, const float* gob,
                                         const float* epsg, int bb, int e) {
  float s = 0.f;
  #pragma unroll
  for (int hb = 0; hb < 16; ++hb) s += part[(bb*16 + hb)*8 + e];
  return s + gob[e] + 1e-4f * epsg[bb*8 + e];
}

// XCD-aware block -> (batch, h-pair): batch b's 16 blocks land on XCD b&7 ->
// per-XCD hot B set = 2 batches' kernels, fits 4MB XCD L2. [T1]
__device__ __forceinline__ void block_map_f(int bid, int* b, int* hb) {
  *b  = (bid & 7) * 2 + (bid >> 7);
  *hb = (bid >> 3) & 15;
}

// ---------------------------------------------------------------------------
// MFMA 3x3 SAME conv, block = (b, h-pair): M=64 (2h x 32w), N=128, K=1152.
// 8 waves: wave = w-half (mpar) x 2 n-frags x both h rows -> 4 MFMA/step.
// A: x staged f32->bf16 (hi[,lo]) into XOR-swizzled LDS; one barrier.
// B: fragment-ordered global, DMA'd per K-step into an LDS ring via
//    global_load_lds (ZERO VGPR in flight -> depth 6/3 vs r6's 3-reg cap).
//    Wave wid stages fragment wid (lane-linear src AND dst -> satisfies the
//    wave-uniform-base rule). Ring R=D+1: stage target = slot consumed LAST
//    step (its ds_reads provably retired via the MFMA lgkmcnt). Counted
//    vmcnt (never 0 in-loop) + one raw s_barrier/step (no drain). [T3/T4]
// NVAR==2: split-precision gating conv (Ah*Bh + Al*Bh + Ah*Bl), epilogue
//          fuses 2x2 maxpool + dense partials -> part[b][hb][8].
// NVAR==1: expert conv, per-batch B; gates+effective-bias computed in-block.
// ---------------------------------------------------------------------------
template<int NVAR>
__global__ __launch_bounds__(512) void conv_k(
    const float* __restrict__ x,
    const bf16* __restrict__ Bhi, const bf16* __restrict__ Blo,
    const float* __restrict__ gb,    // gating conv bias     (NVAR==2)
    const float* __restrict__ Wg,    // gating dense weights (NVAR==2)
    const float* __restrict__ part,  // logit partials       (NVAR==1)
    const float* __restrict__ gob,   // gating out bias      (NVAR==1)
    const float* __restrict__ epsg,  // gate noise           (NVAR==1)
    const float* __restrict__ ebias, // expert bias [F][8]   (NVAR==1)
    float* __restrict__ outv)
{
  constexpr int DEP   = (NVAR == 1) ? 6 : 3;     // pipeline depth (K-steps)
  constexpr int RDEP  = DEP + 1;                 // ring slots
  constexpr int SLOTE = (NVAR == 1) ? 4096 : 8192;  // elems per slot

  int b, hb;
  block_map_f(blockIdx.x, &b, &hb);
  const int t   = threadIdx.x;
  const int l   = t & 63;
  const int wid = t >> 6;

  __shared__ bf16 xs[NVAR*4*34*128];   // 34816 B per variant, swizzled
  __shared__ bf16 bB[RDEP * SLOTE];    // B ring: 57KB / 64KB
  __shared__ float red[8][8];
  __shared__ float gl8[8];

  const bf16* Bh = Bhi + (NVAR == 1 ? (size_t)b * KSZ : (size_t)0);

#define STAGE(KS_) do {                                                     \
    int kk_ = (KS_) < NKS ? (KS_) : NKS-1;                                  \
    int sl_ = ((KS_) % RDEP) * SLOTE + wid*512;                             \
    const bf16* gs_ = Bh + (size_t)kk_*FRAG_ELE + wid*512 + l*8;            \
    __builtin_amdgcn_global_load_lds(                                       \
        (const __attribute__((address_space(1))) void*)gs_,                 \
        (__attribute__((address_space(3))) void*)&bB[sl_], 16, 0, 0);       \
    if (NVAR == 2) {                                                        \
      const bf16* g2_ = Blo + (size_t)kk_*FRAG_ELE + wid*512 + l*8;         \
      __builtin_amdgcn_global_load_lds(                                     \
          (const __attribute__((address_space(1))) void*)g2_,               \
          (__attribute__((address_space(3))) void*)&bB[sl_ + 4096], 16, 0, 0); \
    }                                                                       \
  } while (0)

  // ---- prologue B stages (DMA overlaps the x conversion below) ----
  #pragma unroll
  for (int d = 0; d < DEP; ++d) STAGE(d);

  // ---- stage x (4 rows x 34 cols x 128c), f32 -> bf16 hi(/lo), swizzled ----
  for (int v = t; v < 4*34*32; v += 512) {
    int c4   = v & 31;
    int col  = (v >> 5) % 34;
    int rowi = (v >> 5) / 34;
    int row  = hb*2 - 1 + rowi;
    int w    = col - 1;
    float4 xv = make_float4(0.f, 0.f, 0.f, 0.f);
    if (row >= 0 && row < H_ && w >= 0 && w < W_)
      xv = *(const float4*)&x[((b*H_ + row)*W_ + w)*C_ + c4*4];
    float vv[4] = {xv.x, xv.y, xv.z, xv.w};
    bf16x4 h4, l4;
    #pragma unroll
    for (int j = 0; j < 4; ++j) {
      h4[j] = (bf16)vv[j];
      if (NVAR == 2) l4[j] = (bf16)(vv[j] - (float)h4[j]);
    }
    int base = ((rowi*34 + col)*256 + c4*8) ^ ((col & 7) << 4);
    *(bf16x4*)((char*)xs + base) = h4;
    if (NVAR == 2) *(bf16x4*)((char*)xs + 34816 + base) = l4;
  }
  if (NVAR == 1 && t == 0) {           // gates for this batch (pre-barrier)
    float lg[8], gg[8];
    #pragma unroll
    for (int e = 0; e < 8; ++e) lg[e] = logit_f(part, gob, epsg, b, e);
    top2_gates_f(lg, gg);
    #pragma unroll
    for (int e = 0; e < 8; ++e) gl8[e] = gg[e];
  }
  __syncthreads();   // drains prologue stages too (vmcnt counting unaffected)

  const int mpar = wid & 1;            // w-half
  const int nf0  = (wid >> 1) << 1;    // n-frags nf0, nf0+1
  const int r15  = l & 15;
  const int q    = l >> 4;

  f32x4 acc00 = {0.f,0.f,0.f,0.f}, acc01 = acc00, acc10 = acc00, acc11 = acc00;

#define MFMA16(a, bb_, c) __builtin_amdgcn_mfma_f32_16x16x32_bf16(a, bb_, c, 0, 0, 0)

  for (int ks = 0; ks < NKS; ++ks) {
    // counted wait: own oldest step's stages done; barrier: everyone's done
    if (NVAR == 1) asm volatile("s_waitcnt vmcnt(5)" ::: "memory");
    else           asm volatile("s_waitcnt vmcnt(4)" ::: "memory");
    __builtin_amdgcn_s_barrier();

    const int sb = (ks % RDEP) * SLOTE;
    bf16x8 bh0 = *(const bf16x8*)&bB[sb + nf0*512 + l*8];
    bf16x8 bh1 = *(const bf16x8*)&bB[sb + (nf0+1)*512 + l*8];

    const int khkw = ks >> 2;
    const int kh = khkw / 3, kw = khkw % 3;
    const int c0 = (ks & 3) << 5;
    const int col = mpar*16 + r15 + kw;
    const int off = ((kh*34 + col)*256 + (c0 + q*8)*2) ^ ((col & 7) << 4);
    bf16x8 a0 = *(const bf16x8*)((const char*)xs + off);          // h row 0
    bf16x8 a1 = *(const bf16x8*)((const char*)xs + off + 8704);   // h row 1

    STAGE(ks + DEP);   // into slot consumed at ks-1 (reads retired)

    __builtin_amdgcn_s_setprio(1);
    acc00 = MFMA16(a0, bh0, acc00);
    acc01 = MFMA16(a0, bh1, acc01);
    acc10 = MFMA16(a1, bh0, acc10);
    acc11 = MFMA16(a1, bh1, acc11);
    if (NVAR == 2) {
      bf16x8 bl0 = *(const bf16x8*)&bB[sb + 4096 + nf0*512 + l*8];
      bf16x8 bl1 = *(const bf16x8*)&bB[sb + 4096 + (nf0+1)*512 + l*8];
      bf16x8 g0  = *(const bf16x8*)((const char*)xs + 34816 + off);
      bf16x8 g1  = *(const bf16x8*)((const char*)xs + 34816 + off + 8704);
      acc00 = MFMA16(g0, bh0, acc00);
      acc01 = MFMA16(g0, bh1, acc01);
      acc10 = MFMA16(g1, bh0, acc10);
      acc11 = MFMA16(g1, bh1, acc11);
      acc00 = MFMA16(a0, bl0, acc00);
      acc01 = MFMA16(a0, bl1, acc01);
      acc10 = MFMA16(a1, bl0, acc10);
      acc11 = MFMA16(a1, bl1, acc11);
    }
    __builtin_amdgcn_s_setprio(0);
  }
#undef STAGE
#undef MFMA16
  asm volatile("s_waitcnt vmcnt(0)" ::: "memory");  // drain tail stages

  // C/D layout: col(f) = l&15, row(m within frag) = q*4 + r
  if (NVAR == 1) {
    const int f0 = nf0*16 + r15;
    float bv0 = 0.f, bv1 = 0.f;
    #pragma unroll
    for (int e = 0; e < 8; ++e) {
      bv0 += gl8[e] * ebias[f0*8 + e];
      bv1 += gl8[e] * ebias[(f0+16)*8 + e];
    }
    #pragma unroll
    for (int mi = 0; mi < 2; ++mi) {
      const int h = hb*2 + mi;
      #pragma unroll
      for (int r = 0; r < 4; ++r) {
        const int wo = mpar*16 + q*4 + r;
        float* o = &outv[((b*H_ + h)*W_ + wo)*F_];
        o[f0]      = (mi ? acc10[r] : acc00[r]) + bv0;
        o[f0 + 16] = (mi ? acc11[r] : acc01[r]) + bv1;
      }
    }
  } else {
    float pr[8] = {0,0,0,0,0,0,0,0};
    #pragma unroll
    for (int ni = 0; ni < 2; ++ni) {
      const int f = (nf0 + ni)*16 + r15;
      const float bv = gb[f];
      #pragma unroll
      for (int pp = 0; pp < 2; ++pp) {
        float m0 = ni ? fmaxf(acc01[2*pp], acc01[2*pp+1])
                      : fmaxf(acc00[2*pp], acc00[2*pp+1]);
        float m1 = ni ? fmaxf(acc11[2*pp], acc11[2*pp+1])
                      : fmaxf(acc10[2*pp], acc10[2*pp+1]);
        float pm = fmaxf(m0, m1) + bv;
        const int pw = mpar*8 + q*2 + pp;
        const float* wr = &Wg[(size_t)((hb*16 + pw)*128 + f) * 8];
        float4 wA = *(const float4*)wr;
        float4 wB = *(const float4*)(wr + 4);
        pr[0] += pm*wA.x; pr[1] += pm*wA.y; pr[2] += pm*wA.z; pr[3] += pm*wA.w;
        pr[4] += pm*wB.x; pr[5] += pm*wB.y; pr[6] += pm*wB.z; pr[7] += pm*wB.w;
      }
    }
    #pragma unroll
    for (int o = 32; o > 0; o >>= 1)
      #pragma unroll
      for (int e = 0; e < 8; ++e) pr[e] += __shfl_down(pr[e], o);
    if (l == 0)
      #pragma unroll
      for (int e = 0; e < 8; ++e) red[wid][e] = pr[e];
    __syncthreads();
    if (t < 8) {
      float s = 0.f;
      #pragma unroll
      for (int w = 0; w < 8; ++w) s += red[w][t];
      outv[(b*16 + hb)*8 + t] = s;   // partial logits (16 per batch)
    }
  }
}

// ---------------------------------------------------------------------------
// Effective per-batch kernels in bf16 MFMA fragment order; gates recomputed
// in-block. Block = (ks, nf-half, batch-HALF): grid 144, 8 batches per block
// (mu/eps re-read x2 instead of x4).
// ---------------------------------------------------------------------------
__global__ __launch_bounds__(256) void effk_k(
    const float* __restrict__ mu, const float* __restrict__ rho,
    const float* __restrict__ eps,
    const float* __restrict__ part, const float* __restrict__ gob,
    const float* __restrict__ epsg,
    bf16* __restrict__ Bg)
{
  const int ks  = blockIdx.x >> 2;
  const int rem = blockIdx.x & 3;
  const int t   = threadIdx.x;
  const int nf  = (rem & 1)*4 + (t >> 6);
  const int bq  = (rem >> 1) * 8;

  __shared__ float lgs[8][8];
  __shared__ float gl[8][8];
  if (t < 64) lgs[t >> 3][t & 7] = logit_f(part, gob, epsg, bq + (t >> 3), t & 7);
  __syncthreads();
  if (t < 8) top2_gates_f(lgs[t], gl[t]);
  __syncthreads();

  const int l    = t & 63;
  const int khkw = ks >> 2;
  const int kw   = khkw % 3;
  const int f    = nf*16 + (l & 15);
  const int cb   = (ks & 3)*32 + (l >> 4)*8;

  bf16x8 ob[8];
  #pragma unroll
  for (int j = 0; j < 8; ++j) {
    const int c = cb + j;
    const float* mp = &mu [(size_t)((khkw*C_ + c)*F_ + f) * 8];
    const float* ep = &eps[(size_t)((khkw*C_ + c)*F_ + f) * 8];
    const float* rp = &rho[(size_t)((kw  *C_ + c)*F_ + f) * 8];
    float kv[8];
    #pragma unroll
    for (int e = 0; e < 8; ++e)
      kv[e] = mp[e] + softplus_f(rp[e]) * ep[e];
    #pragma unroll
    for (int bb = 0; bb < 8; ++bb) {
      float s = 0.f;
      #pragma unroll
      for (int e = 0; e < 8; ++e) s += gl[bb][e] * kv[e];
      ob[bb][j] = (bf16)s;
    }
  }
  #pragma unroll
  for (int bb = 0; bb < 8; ++bb) {
    size_t o = (size_t)(bq + bb)*KSZ + (size_t)ks*FRAG_ELE + nf*512 + l*8;
    *(bf16x8*)&Bg[o] = ob[bb];
  }
}

// ---------------------------------------------------------------------------
// gating_kernel f32 -> bf16 hi/lo in fragment order, via coalesced tile load
// + LDS transpose (stride 129: conflict-free reads). Block = one K-step.
// ---------------------------------------------------------------------------
__global__ __launch_bounds__(512) void gkconv_k(
    const float* __restrict__ gk, bf16* __restrict__ bgh, bf16* __restrict__ bgl)
{
  __shared__ float tile[32*129];
  const int ks   = blockIdx.x;
  const int khkw = ks >> 2;
  const int cb   = (ks & 3)*32;
  const int t    = threadIdx.x;

  for (int v = t; v < 1024; v += 512) {          // 32c x 128f, coalesced
    int c  = v >> 5;
    int f4 = (v & 31) * 4;
    float4 val = *(const float4*)&gk[(size_t)(khkw*C_ + cb + c)*F_ + f4];
    float* dst = &tile[c*129 + f4];
    dst[0] = val.x; dst[1] = val.y; dst[2] = val.z; dst[3] = val.w;
  }
  __syncthreads();

  const int nf = t >> 6, l = t & 63;
  const int f  = nf*16 + (l & 15);
  bf16x8 h8, l8;
  #pragma unroll
  for (int j = 0; j < 8; ++j) {
    int c = (l >> 4)*8 + j;
    float v = tile[c*129 + f];
    bf16 h = (bf16)v;
    h8[j] = h;
    l8[j] = (bf16)(v - (float)h);
  }
  *(bf16x8*)&bgh[(size_t)ks*FRAG_ELE + t*8] = h8;
  *(bf16x8*)&bgl[(size_t)ks*FRAG_ELE + t*8] = l8;
}

// ---------------------------------------------------------------------------
extern "C" void kernel_launch(void* const* d_in, const int* in_sizes, int n_in,
                              void* d_out, int out_size, void* d_ws, size_t ws_size,
                              hipStream_t stream) {
  const float* x    = (const float*)d_in[0];
  const float* epsk = (const float*)d_in[1];
  const float* epsg = (const float*)d_in[2];
  const float* mu   = (const float*)d_in[3];
  const float* rho  = (const float*)d_in[4];
  const float* ebias= (const float*)d_in[5];
  const float* gk   = (const float*)d_in[6];
  const float* gb   = (const float*)d_in[7];
  const float* gok  = (const float*)d_in[8];
  const float* gob  = (const float*)d_in[9];
  float* out = (float*)d_out;

  char* ws = (char*)d_ws;
  bf16*  bgh  = (bf16*) (ws);                   //   294,912 B
  bf16*  bgl  = (bf16*) (ws + 294912);          //   294,912 B
  bf16*  bge  = (bf16*) (ws + 589824);          // 4,718,592 B
  float* part = (float*)(ws + 5308416);         //     8,192 B  (~5.3 MB)

  // 1. gating kernel -> bf16 hi/lo fragment order (coalesced)
  gkconv_k<<<NKS, 512, 0, stream>>>(gk, bgh, bgl);
  // 2. gating conv (split bf16, fused pool + dense partials)
  conv_k<2><<<B_*16, 512, 0, stream>>>(x, bgh, bgl, gb, gok,
                                       nullptr, nullptr, nullptr, nullptr, part);
  // 3. per-batch effective kernel (gates recomputed in-block)
  effk_k<<<NKS*4, 256, 0, stream>>>(mu, rho, epsk, part, gob, epsg, bge);
  // 4. expert conv (per-batch kernel; gates + effective bias in-block)
  conv_k<1><<<B_*16, 512, 0, stream>>>(x, bge, bge, nullptr, nullptr,
                                       part, gob, epsg, ebias, out);
}

// Round 9
// 65.491 us; speedup vs baseline: 1.2005x; 1.0729x over previous
//
#include <hip/hip_runtime.h>
#include <cmath>

#define B_ 16
#define H_ 32
#define W_ 32
#define C_ 128
#define F_ 128
#define KSZ (9*C_*F_)        // 147456 elems per effective kernel
#define NKS 36               // K-steps of 32 (9 taps x 4 c-chunks)
#define FRAG_ELE 4096        // elems per K-step fragment chunk

typedef __bf16 bf16;
typedef __bf16 bf16x4 __attribute__((ext_vector_type(4)));
typedef __bf16 bf16x8 __attribute__((ext_vector_type(8)));
typedef float  f32x4  __attribute__((ext_vector_type(4)));

__device__ __forceinline__ float softplus_f(float v) {
  return log1pf(expf(-fabsf(v))) + fmaxf(v, 0.f);
}

// top-2 softmax gates from 8 logits (ties -> lowest index, = lax.top_k)
__device__ __forceinline__ void top2_gates_f(const float* lg, float* gl) {
  int i0 = 0;
  #pragma unroll
  for (int e = 1; e < 8; ++e) if (lg[e] > lg[i0]) i0 = e;
  int i1 = (i0 == 0) ? 1 : 0;
  #pragma unroll
  for (int e = 0; e < 8; ++e) if (e != i0 && lg[e] > lg[i1]) i1 = e;
  float m  = fmaxf(lg[i0], lg[i1]);
  float e0 = expf(lg[i0] - m), e1 = expf(lg[i1] - m);
  float s  = e0 + e1;
  #pragma unroll
  for (int e = 0; e < 8; ++e) gl[e] = 0.f;
  gl[i0] = e0 / s; gl[i1] = e1 / s;
}

// logit for batch bb, expert e from conv<2> partials (16 per batch).
// Bit-identical op order at every call site -> consistent gates everywhere.
__device__ __forceinline__ float logit_f(const float* part, const float* gob,
                                         const float* epsg, int bb, int e) {
  float s = 0.f;
  #pragma unroll
  for (int hb = 0; hb < 16; ++hb) s += part[(bb*16 + hb)*8 + e];
  return s + gob[e] + 1e-4f * epsg[bb*8 + e];
}

// XCD-aware block -> (batch, h-pair): batch b's 16 blocks land on XCD b&7 ->
// per-XCD hot B set = 2 batches' kernels, fits 4MB XCD L2. [T1]
__device__ __forceinline__ void block_map_f(int bid, int* b, int* hb) {
  *b  = (bid & 7) * 2 + (bid >> 7);
  *hb = (bid >> 3) & 15;
}

// ---------------------------------------------------------------------------
// MFMA 3x3 SAME conv, block = (b, h-pair): M=64 (2h x 32w), N=128, K=1152.
// 1024 threads = 16 waves = 4 waves/SIMD (r6's 8-wave blocks were 2/SIMD and
// latency-bound ~4x above throughput floors). K-SPLIT: wave-group kg=0 does
// ks 0..17, kg=1 does ks 18..35 -> serial chain halves, 2x waves hide the
// rest. Partial accs combined via LDS (aliased over dead xs) once at end.
// A: x staged f32->bf16 (hi[,lo]) into XOR-swizzled LDS; one barrier.
// B: fragment-ordered global [ks][nf][lane][8]; 3-slot register pipeline
//    (DEP=3 proven no-spill at the 128-VGPR allocation; 4-6 deep spilled
//    111MB scratch in r4/r5).
// NVAR==2: split-precision gating conv (Ah*Bh + Al*Bh + Ah*Bl), epilogue
//          fuses 2x2 maxpool + dense partials -> part[b][hb][8].
// NVAR==1: expert conv, per-batch B; gates+effective-bias computed in-block.
// ---------------------------------------------------------------------------
template<int NVAR>
__global__ __launch_bounds__(1024, 4) void conv_k(
    const float* __restrict__ x,
    const bf16* __restrict__ Bhi, const bf16* __restrict__ Blo,
    const float* __restrict__ gb,    // gating conv bias     (NVAR==2)
    const float* __restrict__ Wg,    // gating dense weights (NVAR==2)
    const float* __restrict__ part,  // logit partials       (NVAR==1)
    const float* __restrict__ gob,   // gating out bias      (NVAR==1)
    const float* __restrict__ epsg,  // gate noise           (NVAR==1)
    const float* __restrict__ ebias, // expert bias [F][8]   (NVAR==1)
    float* __restrict__ outv)
{
  int b, hb;
  block_map_f(blockIdx.x, &b, &hb);
  const int t   = threadIdx.x;
  const int l   = t & 63;
  const int wid = t >> 6;            // 0..15
  const int kg  = wid >> 3;          // K-group: 0 -> ks 0..17, 1 -> 18..35
  const int w8  = wid & 7;           // role within group (as r6's wid)

  __shared__ bf16 xs[NVAR*4*34*128]; // 34816 B per variant, swizzled
  __shared__ float red[8][8];
  __shared__ float gl8[8];

  // ---- stage x (4 rows x 34 cols x 128c), f32 -> bf16 hi(/lo), swizzled ----
  for (int v = t; v < 4*34*32; v += 1024) {
    int c4   = v & 31;
    int col  = (v >> 5) % 34;
    int rowi = (v >> 5) / 34;
    int row  = hb*2 - 1 + rowi;
    int w    = col - 1;
    float4 xv = make_float4(0.f, 0.f, 0.f, 0.f);
    if (row >= 0 && row < H_ && w >= 0 && w < W_)
      xv = *(const float4*)&x[((b*H_ + row)*W_ + w)*C_ + c4*4];
    float vv[4] = {xv.x, xv.y, xv.z, xv.w};
    bf16x4 h4, l4;
    #pragma unroll
    for (int j = 0; j < 4; ++j) {
      h4[j] = (bf16)vv[j];
      if (NVAR == 2) l4[j] = (bf16)(vv[j] - (float)h4[j]);
    }
    int base = ((rowi*34 + col)*256 + c4*8) ^ ((col & 7) << 4);
    *(bf16x4*)((char*)xs + base) = h4;
    if (NVAR == 2) *(bf16x4*)((char*)xs + 34816 + base) = l4;
  }
  if (NVAR == 1 && t == 0) {           // gates for this batch (pre-barrier)
    float lg[8], gg[8];
    #pragma unroll
    for (int e = 0; e < 8; ++e) lg[e] = logit_f(part, gob, epsg, b, e);
    top2_gates_f(lg, gg);
    #pragma unroll
    for (int e = 0; e < 8; ++e) gl8[e] = gg[e];
  }
  __syncthreads();

  const int mpar = w8 & 1;             // w-half
  const int nf0  = (w8 >> 1) << 1;     // n-frags nf0, nf0+1
  const int r15  = l & 15;
  const int q    = l >> 4;

  f32x4 acc00 = {0.f,0.f,0.f,0.f}, acc01 = acc00, acc10 = acc00, acc11 = acc00;

  const bf16* Bh = Bhi + (NVAR == 1 ? (size_t)b * KSZ : (size_t)0);
  const size_t bgo = (size_t)(nf0*512 + l*8);

  bf16x8 s0h0,s0h1,s0l0,s0l1, s1h0,s1h1,s1l0,s1l1, s2h0,s2h1,s2l0,s2l1;

#define LOADB(S, KS_) do {                                                  \
    int kk_ = (KS_); if (kk_ > NKS-1) kk_ = NKS-1;                          \
    size_t o_ = bgo + (size_t)kk_ * FRAG_ELE;                               \
    S##h0 = *(const bf16x8*)(Bh + o_);                                      \
    S##h1 = *(const bf16x8*)(Bh + o_ + 512);                                \
    if (NVAR == 2) {                                                        \
      S##l0 = *(const bf16x8*)(Blo + o_);                                   \
      S##l1 = *(const bf16x8*)(Blo + o_ + 512);                             \
    }                                                                       \
  } while (0)

#define MFMA16(a, bb_, c) __builtin_amdgcn_mfma_f32_16x16x32_bf16(a, bb_, c, 0, 0, 0)

#define COMPUTE(S, KS_) do {                                                \
    const int khkw_ = (KS_) >> 2;                                           \
    const int kh_ = khkw_ / 3, kw_ = khkw_ % 3;                             \
    const int c0_ = ((KS_) & 3) << 5;                                       \
    const int col_ = mpar*16 + r15 + kw_;                                   \
    const int off_ = ((kh_*34 + col_)*256 + (c0_ + q*8)*2) ^ ((col_ & 7) << 4); \
    bf16x8 a0_ = *(const bf16x8*)((const char*)xs + off_);                  \
    bf16x8 a1_ = *(const bf16x8*)((const char*)xs + off_ + 8704);           \
    __builtin_amdgcn_s_setprio(1);                                          \
    acc00 = MFMA16(a0_, S##h0, acc00);                                      \
    acc01 = MFMA16(a0_, S##h1, acc01);                                      \
    acc10 = MFMA16(a1_, S##h0, acc10);                                      \
    acc11 = MFMA16(a1_, S##h1, acc11);                                      \
    if (NVAR == 2) {                                                        \
      bf16x8 g0_ = *(const bf16x8*)((const char*)xs + 34816 + off_);        \
      bf16x8 g1_ = *(const bf16x8*)((const char*)xs + 34816 + off_ + 8704); \
      acc00 = MFMA16(g0_, S##h0, acc00);                                    \
      acc01 = MFMA16(g0_, S##h1, acc01);                                    \
      acc10 = MFMA16(g1_, S##h0, acc10);                                    \
      acc11 = MFMA16(g1_, S##h1, acc11);                                    \
      acc00 = MFMA16(a0_, S##l0, acc00);                                    \
      acc01 = MFMA16(a0_, S##l1, acc01);                                    \
      acc10 = MFMA16(a1_, S##l0, acc10);                                    \
      acc11 = MFMA16(a1_, S##l1, acc11);                                    \
    }                                                                       \
    __builtin_amdgcn_s_setprio(0);                                          \
  } while (0)

  const int ks0 = kg * (NKS/2);
  LOADB(s0, ks0); LOADB(s1, ks0+1); LOADB(s2, ks0+2);
  for (int ks = ks0; ks < ks0 + NKS/2; ks += 3) {
    COMPUTE(s0, ks);   LOADB(s0, ks+3);
    COMPUTE(s1, ks+1); LOADB(s1, ks+4);
    COMPUTE(s2, ks+2); LOADB(s2, ks+5);
  }
#undef LOADB
#undef COMPUTE

  // ---- combine K-group partial accumulators via LDS (aliased over xs) ----
  __syncthreads();                       // all xs reads done
  float* comb = (float*)xs;              // [8 w8][16 i][64 l] = 32KB, no-conflict
  if (kg == 1) {
    #pragma unroll
    for (int r = 0; r < 4; ++r) {
      comb[(w8*16 + 0  + r)*64 + l] = acc00[r];
      comb[(w8*16 + 4  + r)*64 + l] = acc01[r];
      comb[(w8*16 + 8  + r)*64 + l] = acc10[r];
      comb[(w8*16 + 12 + r)*64 + l] = acc11[r];
    }
  }
  __syncthreads();
  if (kg == 0) {
    #pragma unroll
    for (int r = 0; r < 4; ++r) {
      acc00[r] += comb[(w8*16 + 0  + r)*64 + l];
      acc01[r] += comb[(w8*16 + 4  + r)*64 + l];
      acc10[r] += comb[(w8*16 + 8  + r)*64 + l];
      acc11[r] += comb[(w8*16 + 12 + r)*64 + l];
    }
  }

  // C/D layout: col(f) = l&15, row(m within frag) = q*4 + r
  if (NVAR == 1) {
    if (kg == 0) {
      const int f0 = nf0*16 + r15;
      float bv0 = 0.f, bv1 = 0.f;
      #pragma unroll
      for (int e = 0; e < 8; ++e) {
        bv0 += gl8[e] * ebias[f0*8 + e];
        bv1 += gl8[e] * ebias[(f0+16)*8 + e];
      }
      #pragma unroll
      for (int mi = 0; mi < 2; ++mi) {
        const int h = hb*2 + mi;
        #pragma unroll
        for (int r = 0; r < 4; ++r) {
          const int wo = mpar*16 + q*4 + r;
          float* o = &outv[((b*H_ + h)*W_ + wo)*F_];
          o[f0]      = (mi ? acc10[r] : acc00[r]) + bv0;
          o[f0 + 16] = (mi ? acc11[r] : acc01[r]) + bv1;
        }
      }
    }
  } else {
    float pr[8] = {0,0,0,0,0,0,0,0};
    if (kg == 0) {
      #pragma unroll
      for (int ni = 0; ni < 2; ++ni) {
        const int f = (nf0 + ni)*16 + r15;
        const float bv = gb[f];
        #pragma unroll
        for (int pp = 0; pp < 2; ++pp) {
          float m0 = ni ? fmaxf(acc01[2*pp], acc01[2*pp+1])
                        : fmaxf(acc00[2*pp], acc00[2*pp+1]);
          float m1 = ni ? fmaxf(acc11[2*pp], acc11[2*pp+1])
                        : fmaxf(acc10[2*pp], acc10[2*pp+1]);
          float pm = fmaxf(m0, m1) + bv;
          const int pw = mpar*8 + q*2 + pp;
          const float* wr = &Wg[(size_t)((hb*16 + pw)*128 + f) * 8];
          float4 wA = *(const float4*)wr;
          float4 wB = *(const float4*)(wr + 4);
          pr[0] += pm*wA.x; pr[1] += pm*wA.y; pr[2] += pm*wA.z; pr[3] += pm*wA.w;
          pr[4] += pm*wB.x; pr[5] += pm*wB.y; pr[6] += pm*wB.z; pr[7] += pm*wB.w;
        }
      }
    }
    #pragma unroll
    for (int o = 32; o > 0; o >>= 1)
      #pragma unroll
      for (int e = 0; e < 8; ++e) pr[e] += __shfl_down(pr[e], o);
    if (l == 0 && kg == 0)
      #pragma unroll
      for (int e = 0; e < 8; ++e) red[w8][e] = pr[e];
    __syncthreads();
    if (t < 8) {
      float s = 0.f;
      #pragma unroll
      for (int w = 0; w < 8; ++w) s += red[w][t];
      outv[(b*16 + hb)*8 + t] = s;   // partial logits (16 per batch)
    }
  }
}

// ---------------------------------------------------------------------------
// Effective per-batch kernels in bf16 MFMA fragment order; gates recomputed
// in-block from partials. Block = (ks, nf-half, batch-quarter): grid 288.
// ---------------------------------------------------------------------------
__global__ __launch_bounds__(256) void effk_k(
    const float* __restrict__ mu, const float* __restrict__ rho,
    const float* __restrict__ eps,
    const float* __restrict__ part, const float* __restrict__ gob,
    const float* __restrict__ epsg,
    bf16* __restrict__ Bg)
{
  const int ks  = blockIdx.x >> 3;
  const int rem = blockIdx.x & 7;
  const int t   = threadIdx.x;
  const int nf  = (rem & 1)*4 + (t >> 6);
  const int bq  = (rem >> 1) * 4;

  __shared__ float lgs[4][8];
  __shared__ float gl[4][8];
  if (t < 32) lgs[t >> 3][t & 7] = logit_f(part, gob, epsg, bq + (t >> 3), t & 7);
  __syncthreads();
  if (t < 4) top2_gates_f(lgs[t], gl[t]);
  __syncthreads();

  const int l    = t & 63;
  const int khkw = ks >> 2;
  const int kw   = khkw % 3;
  const int f    = nf*16 + (l & 15);
  const int cb   = (ks & 3)*32 + (l >> 4)*8;

  bf16x8 ob[4];
  #pragma unroll
  for (int j = 0; j < 8; ++j) {
    const int c = cb + j;
    const float* mp = &mu [(size_t)((khkw*C_ + c)*F_ + f) * 8];
    const float* ep = &eps[(size_t)((khkw*C_ + c)*F_ + f) * 8];
    const float* rp = &rho[(size_t)((kw  *C_ + c)*F_ + f) * 8];
    float kv[8];
    #pragma unroll
    for (int e = 0; e < 8; ++e)
      kv[e] = mp[e] + softplus_f(rp[e]) * ep[e];
    #pragma unroll
    for (int bb = 0; bb < 4; ++bb) {
      float s = 0.f;
      #pragma unroll
      for (int e = 0; e < 8; ++e) s += gl[bb][e] * kv[e];
      ob[bb][j] = (bf16)s;
    }
  }
  #pragma unroll
  for (int bb = 0; bb < 4; ++bb) {
    size_t o = (size_t)(bq + bb)*KSZ + (size_t)ks*FRAG_ELE + nf*512 + l*8;
    *(bf16x8*)&Bg[o] = ob[bb];
  }
}

// ---------------------------------------------------------------------------
// gating_kernel f32 -> bf16 hi/lo in fragment order, via coalesced tile load
// + LDS transpose (stride 129: conflict-free reads). Block = one K-step.
// ---------------------------------------------------------------------------
__global__ __launch_bounds__(512) void gkconv_k(
    const float* __restrict__ gk, bf16* __restrict__ bgh, bf16* __restrict__ bgl)
{
  __shared__ float tile[32*129];
  const int ks   = blockIdx.x;
  const int khkw = ks >> 2;
  const int cb   = (ks & 3)*32;
  const int t    = threadIdx.x;

  for (int v = t; v < 1024; v += 512) {          // 32c x 128f, coalesced
    int c  = v >> 5;
    int f4 = (v & 31) * 4;
    float4 val = *(const float4*)&gk[(size_t)(khkw*C_ + cb + c)*F_ + f4];
    float* dst = &tile[c*129 + f4];
    dst[0] = val.x; dst[1] = val.y; dst[2] = val.z; dst[3] = val.w;
  }
  __syncthreads();

  const int nf = t >> 6, l = t & 63;
  const int f  = nf*16 + (l & 15);
  bf16x8 h8, l8;
  #pragma unroll
  for (int j = 0; j < 8; ++j) {
    int c = (l >> 4)*8 + j;
    float v = tile[c*129 + f];
    bf16 h = (bf16)v;
    h8[j] = h;
    l8[j] = (bf16)(v - (float)h);
  }
  *(bf16x8*)&bgh[(size_t)ks*FRAG_ELE + t*8] = h8;
  *(bf16x8*)&bgl[(size_t)ks*FRAG_ELE + t*8] = l8;
}

// ---------------------------------------------------------------------------
extern "C" void kernel_launch(void* const* d_in, const int* in_sizes, int n_in,
                              void* d_out, int out_size, void* d_ws, size_t ws_size,
                              hipStream_t stream) {
  const float* x    = (const float*)d_in[0];
  const float* epsk = (const float*)d_in[1];
  const float* epsg = (const float*)d_in[2];
  const float* mu   = (const float*)d_in[3];
  const float* rho  = (const float*)d_in[4];
  const float* ebias= (const float*)d_in[5];
  const float* gk   = (const float*)d_in[6];
  const float* gb   = (const float*)d_in[7];
  const float* gok  = (const float*)d_in[8];
  const float* gob  = (const float*)d_in[9];
  float* out = (float*)d_out;

  char* ws = (char*)d_ws;
  bf16*  bgh  = (bf16*) (ws);                   //   294,912 B
  bf16*  bgl  = (bf16*) (ws + 294912);          //   294,912 B
  bf16*  bge  = (bf16*) (ws + 589824);          // 4,718,592 B
  float* part = (float*)(ws + 5308416);         //     8,192 B  (~5.3 MB)

  // 1. gating kernel -> bf16 hi/lo fragment order (coalesced)
  gkconv_k<<<NKS, 512, 0, stream>>>(gk, bgh, bgl);
  // 2. gating conv (split bf16, K-split 16 waves, fused pool + dense partials)
  conv_k<2><<<B_*16, 1024, 0, stream>>>(x, bgh, bgl, gb, gok,
                                        nullptr, nullptr, nullptr, nullptr, part);
  // 3. per-batch effective kernel (gates recomputed in-block)
  effk_k<<<NKS*8, 256, 0, stream>>>(mu, rho, epsk, part, gob, epsg, bge);
  // 4. expert conv (per-batch kernel; gates + effective bias in-block)
  conv_k<1><<<B_*16, 1024, 0, stream>>>(x, bge, bge, nullptr, nullptr,
                                        part, gob, epsg, ebias, out);
}

// Round 10
// 55.625 us; speedup vs baseline: 1.4135x; 1.1774x over previous
//
#include <hip/hip_runtime.h>
#include <cmath>

#define B_ 16
#define H_ 32
#define W_ 32
#define C_ 128
#define F_ 128
#define KSZ (9*C_*F_)        // 147456 elems per expert kernel
#define NKS 36               // K-steps of 32 (9 taps x 4 c-chunks)
#define FRAG_ELE 4096        // elems per K-step fragment chunk

typedef __bf16 bf16;
typedef __bf16 bf16x4 __attribute__((ext_vector_type(4)));
typedef __bf16 bf16x8 __attribute__((ext_vector_type(8)));
typedef float  f32x4  __attribute__((ext_vector_type(4)));

__device__ __forceinline__ float softplus_f(float v) {
  return log1pf(expf(-fabsf(v))) + fmaxf(v, 0.f);
}

// logit for batch bb, expert e from conv<2> partials (16 per batch).
// Bit-identical op order at every call site -> consistent gates everywhere.
__device__ __forceinline__ float logit_f(const float* part, const float* gob,
                                         const float* epsg, int bb, int e) {
  float s = 0.f;
  #pragma unroll
  for (int hb = 0; hb < 16; ++hb) s += part[(bb*16 + hb)*8 + e];
  return s + gob[e] + 1e-4f * epsg[bb*8 + e];
}

// XCD-aware block -> (batch, h-pair): batch b's 16 blocks land on XCD b&7. [T1]
__device__ __forceinline__ void block_map_f(int bid, int* b, int* hb) {
  *b  = (bid & 7) * 2 + (bid >> 7);
  *hb = (bid >> 3) & 15;
}

// ---------------------------------------------------------------------------
// MFMA 3x3 SAME conv, block = (b, h-pair): M=64 (2h x 32w), N=128, K=1152.
// 1024 threads = 16 waves, K-SPLIT (kg=0: ks 0..17, kg=1: 18..35), partial
// accs combined via LDS (aliased over dead xs). r9 structure verbatim.
// B: fragment-ordered global, 3-slot register pipeline (DEP=3 proven
//    no-spill at the 128-VGPR allocation; 4-6 deep spilled in r4/r5).
// MODE==2: gating conv, split-precision (Ah*Bh + Al*Bh + Ah*Bl), epilogue
//          fuses 2x2 maxpool + dense partials -> part[b][hb][8].
// MODE==1: expert conv via TOP-2 BANK: B0/B1 = the two selected experts'
//          fragment banks (gate-independent prep!), dual acc sets, epilogue
//          merges out = g0*accA + g1*accB + gates-weighted bias.
// ---------------------------------------------------------------------------
template<int MODE>
__global__ __launch_bounds__(1024, 4) void conv_k(
    const float* __restrict__ x,
    const bf16* __restrict__ Bhi,    // MODE2: gk-hi frags; MODE1: expert bank
    const bf16* __restrict__ Blo,    // MODE2: gk-lo frags; MODE1: unused
    const float* __restrict__ gb,    // gating conv bias     (MODE==2)
    const float* __restrict__ Wg,    // gating dense weights (MODE==2)
    const float* __restrict__ part,  // logit partials       (MODE==1)
    const float* __restrict__ gob,   // gating out bias      (MODE==1)
    const float* __restrict__ epsg,  // gate noise           (MODE==1)
    const float* __restrict__ ebias, // expert bias [F][8]   (MODE==1)
    float* __restrict__ outv)
{
  int b, hb;
  block_map_f(blockIdx.x, &b, &hb);
  const int t   = threadIdx.x;
  const int l   = t & 63;
  const int wid = t >> 6;            // 0..15
  const int kg  = wid >> 3;          // K-group
  const int w8  = wid & 7;

  __shared__ bf16 xs[MODE*4*34*128]; // 34816 B per variant, swizzled
  __shared__ float red[8][8];
  __shared__ float gl8[8];
  __shared__ float gw2[2];
  __shared__ int   eid2[2];

  // ---- stage x (4 rows x 34 cols x 128c), f32 -> bf16 hi(/lo), swizzled ----
  for (int v = t; v < 4*34*32; v += 1024) {
    int c4   = v & 31;
    int col  = (v >> 5) % 34;
    int rowi = (v >> 5) / 34;
    int row  = hb*2 - 1 + rowi;
    int w    = col - 1;
    float4 xv = make_float4(0.f, 0.f, 0.f, 0.f);
    if (row >= 0 && row < H_ && w >= 0 && w < W_)
      xv = *(const float4*)&x[((b*H_ + row)*W_ + w)*C_ + c4*4];
    float vv[4] = {xv.x, xv.y, xv.z, xv.w};
    bf16x4 h4, l4;
    #pragma unroll
    for (int j = 0; j < 4; ++j) {
      h4[j] = (bf16)vv[j];
      if (MODE == 2) l4[j] = (bf16)(vv[j] - (float)h4[j]);
    }
    int base = ((rowi*34 + col)*256 + c4*8) ^ ((col & 7) << 4);
    *(bf16x4*)((char*)xs + base) = h4;
    if (MODE == 2) *(bf16x4*)((char*)xs + 34816 + base) = l4;
  }
  if (MODE == 1 && t == 0) {         // gates + top-2 ids for this batch
    float lg[8];
    #pragma unroll
    for (int e = 0; e < 8; ++e) lg[e] = logit_f(part, gob, epsg, b, e);
    int i0 = 0;
    #pragma unroll
    for (int e = 1; e < 8; ++e) if (lg[e] > lg[i0]) i0 = e;
    int i1 = (i0 == 0) ? 1 : 0;
    #pragma unroll
    for (int e = 0; e < 8; ++e) if (e != i0 && lg[e] > lg[i1]) i1 = e;
    float m  = fmaxf(lg[i0], lg[i1]);
    float e0 = expf(lg[i0] - m), e1 = expf(lg[i1] - m);
    float s  = e0 + e1;
    #pragma unroll
    for (int e = 0; e < 8; ++e) gl8[e] = 0.f;
    gl8[i0] = e0 / s;  gl8[i1] = e1 / s;
    eid2[0] = i0;      eid2[1] = i1;
    gw2[0]  = e0 / s;  gw2[1]  = e1 / s;
  }
  __syncthreads();

  const int mpar = w8 & 1;             // w-half
  const int nf0  = (w8 >> 1) << 1;     // n-frags nf0, nf0+1
  const int r15  = l & 15;
  const int q    = l >> 4;

  f32x4 acc00 = {0.f,0.f,0.f,0.f}, acc01 = acc00, acc10 = acc00, acc11 = acc00;
  f32x4 acd00 = acc00, acd01 = acc00, acd10 = acc00, acd11 = acc00; // MODE1: expert B

  const bf16* B0;
  const bf16* B1;
  if (MODE == 1) { B0 = Bhi + (size_t)eid2[0]*KSZ; B1 = Bhi + (size_t)eid2[1]*KSZ; }
  else           { B0 = Bhi;                       B1 = Blo; }
  const size_t bgo = (size_t)(nf0*512 + l*8);

  bf16x8 s0h0,s0h1,s0l0,s0l1, s1h0,s1h1,s1l0,s1l1, s2h0,s2h1,s2l0,s2l1;

#define LOADB(S, KS_) do {                                                  \
    int kk_ = (KS_); if (kk_ > NKS-1) kk_ = NKS-1;                          \
    size_t o_ = bgo + (size_t)kk_ * FRAG_ELE;                               \
    S##h0 = *(const bf16x8*)(B0 + o_);                                      \
    S##h1 = *(const bf16x8*)(B0 + o_ + 512);                                \
    S##l0 = *(const bf16x8*)(B1 + o_);                                      \
    S##l1 = *(const bf16x8*)(B1 + o_ + 512);                                \
  } while (0)

#define MFMA16(a, bb_, c) __builtin_amdgcn_mfma_f32_16x16x32_bf16(a, bb_, c, 0, 0, 0)

#define COMPUTE(S, KS_) do {                                                \
    const int khkw_ = (KS_) >> 2;                                           \
    const int kh_ = khkw_ / 3, kw_ = khkw_ % 3;                             \
    const int c0_ = ((KS_) & 3) << 5;                                       \
    const int col_ = mpar*16 + r15 + kw_;                                   \
    const int off_ = ((kh_*34 + col_)*256 + (c0_ + q*8)*2) ^ ((col_ & 7) << 4); \
    bf16x8 a0_ = *(const bf16x8*)((const char*)xs + off_);                  \
    bf16x8 a1_ = *(const bf16x8*)((const char*)xs + off_ + 8704);           \
    __builtin_amdgcn_s_setprio(1);                                          \
    acc00 = MFMA16(a0_, S##h0, acc00);                                      \
    acc01 = MFMA16(a0_, S##h1, acc01);                                      \
    acc10 = MFMA16(a1_, S##h0, acc10);                                      \
    acc11 = MFMA16(a1_, S##h1, acc11);                                      \
    if (MODE == 2) {                                                        \
      bf16x8 g0_ = *(const bf16x8*)((const char*)xs + 34816 + off_);        \
      bf16x8 g1_ = *(const bf16x8*)((const char*)xs + 34816 + off_ + 8704); \
      acc00 = MFMA16(g0_, S##h0, acc00);                                    \
      acc01 = MFMA16(g0_, S##h1, acc01);                                    \
      acc10 = MFMA16(g1_, S##h0, acc10);                                    \
      acc11 = MFMA16(g1_, S##h1, acc11);                                    \
      acc00 = MFMA16(a0_, S##l0, acc00);                                    \
      acc01 = MFMA16(a0_, S##l1, acc01);                                    \
      acc10 = MFMA16(a1_, S##l0, acc10);                                    \
      acc11 = MFMA16(a1_, S##l1, acc11);                                    \
    } else {                                                                \
      acd00 = MFMA16(a0_, S##l0, acd00);                                    \
      acd01 = MFMA16(a0_, S##l1, acd01);                                    \
      acd10 = MFMA16(a1_, S##l0, acd10);                                    \
      acd11 = MFMA16(a1_, S##l1, acd11);                                    \
    }                                                                       \
    __builtin_amdgcn_s_setprio(0);                                          \
  } while (0)

  const int ks0 = kg * (NKS/2);
  LOADB(s0, ks0); LOADB(s1, ks0+1); LOADB(s2, ks0+2);
  for (int ks = ks0; ks < ks0 + NKS/2; ks += 3) {
    COMPUTE(s0, ks);   LOADB(s0, ks+3);
    COMPUTE(s1, ks+1); LOADB(s1, ks+4);
    COMPUTE(s2, ks+2); LOADB(s2, ks+5);
  }
#undef LOADB
#undef COMPUTE

  // ---- MODE1: gate-weighted merge of the two expert accs (linear in K,
  //      so valid per K-group partial) ----
  if (MODE == 1) {
    const float g0 = gw2[0], g1 = gw2[1];
    #pragma unroll
    for (int r = 0; r < 4; ++r) {
      acc00[r] = g0*acc00[r] + g1*acd00[r];
      acc01[r] = g0*acc01[r] + g1*acd01[r];
      acc10[r] = g0*acc10[r] + g1*acd10[r];
      acc11[r] = g0*acc11[r] + g1*acd11[r];
    }
  }

  // ---- combine K-group partial accumulators via LDS (aliased over xs) ----
  __syncthreads();                       // all xs reads done
  float* comb = (float*)xs;              // [8 w8][16 i][64 l] = 32KB
  if (kg == 1) {
    #pragma unroll
    for (int r = 0; r < 4; ++r) {
      comb[(w8*16 + 0  + r)*64 + l] = acc00[r];
      comb[(w8*16 + 4  + r)*64 + l] = acc01[r];
      comb[(w8*16 + 8  + r)*64 + l] = acc10[r];
      comb[(w8*16 + 12 + r)*64 + l] = acc11[r];
    }
  }
  __syncthreads();
  if (kg == 0) {
    #pragma unroll
    for (int r = 0; r < 4; ++r) {
      acc00[r] += comb[(w8*16 + 0  + r)*64 + l];
      acc01[r] += comb[(w8*16 + 4  + r)*64 + l];
      acc10[r] += comb[(w8*16 + 8  + r)*64 + l];
      acc11[r] += comb[(w8*16 + 12 + r)*64 + l];
    }
  }

  // C/D layout: col(f) = l&15, row(m within frag) = q*4 + r
  if (MODE == 1) {
    if (kg == 0) {
      const int f0 = nf0*16 + r15;
      float bv0 = 0.f, bv1 = 0.f;
      #pragma unroll
      for (int e = 0; e < 8; ++e) {
        bv0 += gl8[e] * ebias[f0*8 + e];
        bv1 += gl8[e] * ebias[(f0+16)*8 + e];
      }
      #pragma unroll
      for (int mi = 0; mi < 2; ++mi) {
        const int h = hb*2 + mi;
        #pragma unroll
        for (int r = 0; r < 4; ++r) {
          const int wo = mpar*16 + q*4 + r;
          float* o = &outv[((b*H_ + h)*W_ + wo)*F_];
          o[f0]      = (mi ? acc10[r] : acc00[r]) + bv0;
          o[f0 + 16] = (mi ? acc11[r] : acc01[r]) + bv1;
        }
      }
    }
  } else {
    float pr[8] = {0,0,0,0,0,0,0,0};
    if (kg == 0) {
      #pragma unroll
      for (int ni = 0; ni < 2; ++ni) {
        const int f = (nf0 + ni)*16 + r15;
        const float bv = gb[f];
        #pragma unroll
        for (int pp = 0; pp < 2; ++pp) {
          float m0 = ni ? fmaxf(acc01[2*pp], acc01[2*pp+1])
                        : fmaxf(acc00[2*pp], acc00[2*pp+1]);
          float m1 = ni ? fmaxf(acc11[2*pp], acc11[2*pp+1])
                        : fmaxf(acc10[2*pp], acc10[2*pp+1]);
          float pm = fmaxf(m0, m1) + bv;
          const int pw = mpar*8 + q*2 + pp;
          const float* wr = &Wg[(size_t)((hb*16 + pw)*128 + f) * 8];
          float4 wA = *(const float4*)wr;
          float4 wB = *(const float4*)(wr + 4);
          pr[0] += pm*wA.x; pr[1] += pm*wA.y; pr[2] += pm*wA.z; pr[3] += pm*wA.w;
          pr[4] += pm*wB.x; pr[5] += pm*wB.y; pr[6] += pm*wB.z; pr[7] += pm*wB.w;
        }
      }
    }
    #pragma unroll
    for (int o = 32; o > 0; o >>= 1)
      #pragma unroll
      for (int e = 0; e < 8; ++e) pr[e] += __shfl_down(pr[e], o);
    if (l == 0 && kg == 0)
      #pragma unroll
      for (int e = 0; e < 8; ++e) red[w8][e] = pr[e];
    __syncthreads();
    if (t < 8) {
      float s = 0.f;
      #pragma unroll
      for (int w = 0; w < 8; ++w) s += red[w][t];
      outv[(b*16 + hb)*8 + t] = s;   // partial logits (16 per batch)
    }
  }
}

// ---------------------------------------------------------------------------
// PREP (gate-independent, runs first, off the gating critical path):
//  blocks 0..71: per-EXPERT bf16 kernel bank in fragment order:
//    bank[e][ks][nf][lane][8] = mu + softplus(rho)*eps   (mu/eps read ONCE)
//  blocks 72..107: gating_kernel f32 -> bf16 hi/lo frag order via LDS
//    transpose (stride 129, conflict-free).
// ---------------------------------------------------------------------------
__global__ __launch_bounds__(256) void prep_k(
    const float* __restrict__ mu, const float* __restrict__ rho,
    const float* __restrict__ eps, const float* __restrict__ gk,
    bf16* __restrict__ bank, bf16* __restrict__ bgh, bf16* __restrict__ bgl)
{
  __shared__ float tile[32*129];
  const int bid = blockIdx.x;
  const int t   = threadIdx.x;

  if (bid < 2*NKS) {                   // ---- expert bank ----
    const int ks = bid >> 1;
    const int nf = (bid & 1)*4 + (t >> 6);
    const int l  = t & 63;
    const int khkw = ks >> 2;
    const int kw   = khkw % 3;
    const int f    = nf*16 + (l & 15);
    const int cb   = (ks & 3)*32 + (l >> 4)*8;

    bf16x8 ob[8];
    #pragma unroll
    for (int j = 0; j < 8; ++j) {
      const int c = cb + j;
      const float* mp = &mu [(size_t)((khkw*C_ + c)*F_ + f) * 8];
      const float* ep = &eps[(size_t)((khkw*C_ + c)*F_ + f) * 8];
      const float* rp = &rho[(size_t)((kw  *C_ + c)*F_ + f) * 8];
      #pragma unroll
      for (int e = 0; e < 8; ++e)
        ob[e][j] = (bf16)(mp[e] + softplus_f(rp[e]) * ep[e]);
    }
    #pragma unroll
    for (int e = 0; e < 8; ++e) {
      size_t o = (size_t)e*KSZ + (size_t)ks*FRAG_ELE + nf*512 + l*8;
      *(bf16x8*)&bank[o] = ob[e];
    }
  } else {                             // ---- gk hi/lo conversion ----
    const int ks   = bid - 2*NKS;
    const int khkw = ks >> 2;
    const int cb   = (ks & 3)*32;
    for (int v = t; v < 1024; v += 256) {        // 32c x 128f, coalesced
      int c  = v >> 5;
      int f4 = (v & 31) * 4;
      float4 val = *(const float4*)&gk[(size_t)(khkw*C_ + cb + c)*F_ + f4];
      float* dst = &tile[c*129 + f4];
      dst[0] = val.x; dst[1] = val.y; dst[2] = val.z; dst[3] = val.w;
    }
    __syncthreads();
    for (int tt = t; tt < 512; tt += 256) {
      const int nf = tt >> 6, l = tt & 63;
      const int f  = nf*16 + (l & 15);
      bf16x8 h8, l8;
      #pragma unroll
      for (int j = 0; j < 8; ++j) {
        int c = (l >> 4)*8 + j;
        float v = tile[c*129 + f];
        bf16 h = (bf16)v;
        h8[j] = h;
        l8[j] = (bf16)(v - (float)h);
      }
      *(bf16x8*)&bgh[(size_t)ks*FRAG_ELE + tt*8] = h8;
      *(bf16x8*)&bgl[(size_t)ks*FRAG_ELE + tt*8] = l8;
    }
  }
}

// ---------------------------------------------------------------------------
extern "C" void kernel_launch(void* const* d_in, const int* in_sizes, int n_in,
                              void* d_out, int out_size, void* d_ws, size_t ws_size,
                              hipStream_t stream) {
  const float* x    = (const float*)d_in[0];
  const float* epsk = (const float*)d_in[1];
  const float* epsg = (const float*)d_in[2];
  const float* mu   = (const float*)d_in[3];
  const float* rho  = (const float*)d_in[4];
  const float* ebias= (const float*)d_in[5];
  const float* gk   = (const float*)d_in[6];
  const float* gb   = (const float*)d_in[7];
  const float* gok  = (const float*)d_in[8];
  const float* gob  = (const float*)d_in[9];
  float* out = (float*)d_out;

  char* ws = (char*)d_ws;
  bf16*  bank = (bf16*) (ws);                   // 2,359,296 B (8 experts)
  bf16*  bgh  = (bf16*) (ws + 2359296);         //   294,912 B
  bf16*  bgl  = (bf16*) (ws + 2654208);         //   294,912 B
  float* part = (float*)(ws + 2949120);         //     8,192 B  (~3 MB)

  // 1. prep: expert bank (gate-independent!) + gk hi/lo conversion
  prep_k<<<3*NKS, 256, 0, stream>>>(mu, rho, epsk, gk, bank, bgh, bgl);
  // 2. gating conv (split bf16, K-split 16 waves, fused pool + dense partials)
  conv_k<2><<<B_*16, 1024, 0, stream>>>(x, bgh, bgl, gb, gok,
                                        nullptr, nullptr, nullptr, nullptr, part);
  // 3. expert conv: top-2 bank conv, gates + weighted merge in-block
  conv_k<1><<<B_*16, 1024, 0, stream>>>(x, bank, nullptr, nullptr, nullptr,
                                        part, gob, epsg, ebias, out);
}